// Round 1
// baseline (184.970 us; speedup 1.0000x reference)
//
#include <hip/hip_runtime.h>

#define BATCH 8
#define NPTS  4096
#define CHUNK 1024
#define BLOCK 256

// Each thread owns one query point; block stages a CHUNK of target points in
// LDS; thread computes min squared distance over the chunk, then atomicMin
// (uint bit-pattern trick, valid since d2 >= 0) into the per-query slot.
__global__ __launch_bounds__(BLOCK) void chamfer_min_kernel(
    const float* __restrict__ query,    // [BATCH, NPTS, 3]
    const float* __restrict__ target,   // [BATCH, NPTS, 3]
    unsigned int* __restrict__ out_min) // [BATCH*NPTS] min d2 as uint bits
{
    __shared__ float s[CHUNK * 3];

    const int b  = blockIdx.z;
    const int q  = blockIdx.x * BLOCK + threadIdx.x;
    const int c0 = blockIdx.y * CHUNK;

    // Stage target chunk into LDS with float4 loads (CHUNK*3 floats = 768 float4)
    const float4* src = reinterpret_cast<const float4*>(
        target + (size_t)b * NPTS * 3 + (size_t)c0 * 3);
    float4* dst = reinterpret_cast<float4*>(s);
#pragma unroll
    for (int i = 0; i < (CHUNK * 3 / 4) / BLOCK; ++i) {
        dst[threadIdx.x + i * BLOCK] = src[threadIdx.x + i * BLOCK];
    }
    __syncthreads();

    const float* qp = query + (size_t)b * NPTS * 3 + (size_t)q * 3;
    const float px = qp[0];
    const float py = qp[1];
    const float pz = qp[2];

    float m = 3.0e38f;
#pragma unroll 8
    for (int t = 0; t < CHUNK; ++t) {
        const float dx = px - s[3 * t + 0];
        const float dy = py - s[3 * t + 1];
        const float dz = pz - s[3 * t + 2];
        const float d2 = fmaf(dz, dz, fmaf(dy, dy, dx * dx));
        m = fminf(m, d2);
    }

    atomicMin(&out_min[b * NPTS + q], __float_as_uint(m));
}

// Deterministic single-block reduction: sum sqrt(min d2) over both arrays,
// divide by B*N (== B*M), write the scalar.
__global__ __launch_bounds__(1024) void chamfer_reduce_kernel(
    const unsigned int* __restrict__ mins, // [2*BATCH*NPTS]
    float* __restrict__ out)
{
    const int tid = threadIdx.x;
    const int total = 2 * BATCH * NPTS;

    double acc = 0.0;
    for (int i = tid; i < total; i += 1024) {
        acc += (double)sqrtf(__uint_as_float(mins[i]));
    }

    __shared__ double sd[1024];
    sd[tid] = acc;
    __syncthreads();
    for (int off = 512; off > 0; off >>= 1) {
        if (tid < off) sd[tid] += sd[tid + off];
        __syncthreads();
    }
    if (tid == 0) {
        out[0] = (float)(sd[0] / (double)(BATCH * NPTS));
    }
}

extern "C" void kernel_launch(void* const* d_in, const int* in_sizes, int n_in,
                              void* d_out, int out_size, void* d_ws, size_t ws_size,
                              hipStream_t stream) {
    const float* pred = (const float*)d_in[0]; // [8,4096,3]
    const float* gt   = (const float*)d_in[1]; // [8,4096,3]

    unsigned int* min_pred = (unsigned int*)d_ws;              // chamfer2: per (b,n) min over m
    unsigned int* min_gt   = min_pred + BATCH * NPTS;          // chamfer1: per (b,m) min over n

    // Init both min arrays to 0x7F7F7F7F = 3.39e38f (acts as +inf; byte-memset ok)
    hipMemsetAsync(d_ws, 0x7F, (size_t)2 * BATCH * NPTS * sizeof(unsigned int), stream);

    dim3 grid(NPTS / BLOCK, NPTS / CHUNK, BATCH);
    // Pass A: query = pred, target = gt  -> min over m for each (b,n)
    chamfer_min_kernel<<<grid, BLOCK, 0, stream>>>(pred, gt, min_pred);
    // Pass B: query = gt, target = pred  -> min over n for each (b,m)
    chamfer_min_kernel<<<grid, BLOCK, 0, stream>>>(gt, pred, min_gt);

    chamfer_reduce_kernel<<<1, 1024, 0, stream>>>(min_pred, (float*)d_out);
}

// Round 2
// 50.397 us; speedup vs baseline: 3.6702x; 3.6702x over previous
//
#include <hip/hip_runtime.h>

#define BATCH 8
#define NPTS  4096
#define BLOCK 256
#define Q     8              // query points per thread
#define CHUNK 256            // target points staged in LDS per block
// grid: x = NPTS/(BLOCK*Q) = 2 n-blocks, y = NPTS/CHUNK = 16 m-chunks,
//       z = 16 (batch 0..7 for pass A, 8..15 for pass B) -> 512 blocks total

__global__ __launch_bounds__(BLOCK) void chamfer_min_kernel(
    const float* __restrict__ pred,      // [8,4096,3]
    const float* __restrict__ gt,        // [8,4096,3]
    unsigned int* __restrict__ min_pred, // [8*4096] min d2 (pred->gt) as uint bits
    unsigned int* __restrict__ min_gt)   // [8*4096] min d2 (gt->pred)
{
    const int z    = blockIdx.z;
    const int b    = z & 7;
    const int pass = z >> 3;
    const float* query   = pass ? gt   : pred;
    const float* target  = pass ? pred : gt;
    unsigned int* outmin = pass ? min_gt : min_pred;

    __shared__ float4 s4[CHUNK * 3 / 4]; // 192 float4 = 256 points

    const int tid   = threadIdx.x;
    const int nbase = blockIdx.x * (BLOCK * Q);
    const int c0    = blockIdx.y * CHUNK;

    // Stage CHUNK target points into LDS (float4 granularity)
    if (tid < CHUNK * 3 / 4) {
        s4[tid] = reinterpret_cast<const float4*>(
            target + (size_t)b * NPTS * 3 + (size_t)c0 * 3)[tid];
    }

    // Load Q query points into registers (coalesced: stride-BLOCK point index)
    float qx[Q], qy[Q], qz[Q], mn[Q];
#pragma unroll
    for (int i = 0; i < Q; ++i) {
        const float* qp = query + (size_t)b * NPTS * 3
                        + (size_t)(nbase + i * BLOCK + tid) * 3;
        qx[i] = qp[0]; qy[i] = qp[1]; qz[i] = qp[2];
        mn[i] = 3.0e38f;
    }
    __syncthreads();

    // 4 targets per iteration via 3 broadcast ds_read_b128
#pragma unroll 2
    for (int g = 0; g < CHUNK / 4; ++g) {
        const float4 f0 = s4[g * 3 + 0];
        const float4 f1 = s4[g * 3 + 1];
        const float4 f2 = s4[g * 3 + 2];
        const float tx[4] = {f0.x, f0.w, f1.z, f2.y};
        const float ty[4] = {f0.y, f1.x, f1.w, f2.z};
        const float tz[4] = {f0.z, f1.y, f2.x, f2.w};
#pragma unroll
        for (int t = 0; t < 4; ++t) {
#pragma unroll
            for (int i = 0; i < Q; ++i) {
                const float dx = qx[i] - tx[t];
                const float dy = qy[i] - ty[t];
                const float dz = qz[i] - tz[t];
                const float d2 = fmaf(dz, dz, fmaf(dy, dy, dx * dx));
                mn[i] = fminf(mn[i], d2);
            }
        }
    }

    // Coalesced global atomicMin (uint bit-trick valid for non-negative floats)
#pragma unroll
    for (int i = 0; i < Q; ++i) {
        atomicMin(&outmin[b * NPTS + nbase + i * BLOCK + tid],
                  __float_as_uint(mn[i]));
    }
}

// Deterministic single-block reduction: (sum sqrt(min d2) over both arrays)/32768
__global__ __launch_bounds__(1024) void chamfer_reduce_kernel(
    const uint4* __restrict__ mins, // 2*8*4096 uints = 16384 uint4
    float* __restrict__ out)
{
    const int tid = threadIdx.x;
    double acc = 0.0;
#pragma unroll
    for (int i = 0; i < 16; ++i) {
        const uint4 v = mins[tid + i * 1024];
        acc += (double)(sqrtf(__uint_as_float(v.x)) + sqrtf(__uint_as_float(v.y))
                      + sqrtf(__uint_as_float(v.z)) + sqrtf(__uint_as_float(v.w)));
    }
    __shared__ double sd[1024];
    sd[tid] = acc;
    __syncthreads();
    for (int off = 512; off > 0; off >>= 1) {
        if (tid < off) sd[tid] += sd[tid + off];
        __syncthreads();
    }
    if (tid == 0) out[0] = (float)(sd[0] / (double)(BATCH * NPTS));
}

extern "C" void kernel_launch(void* const* d_in, const int* in_sizes, int n_in,
                              void* d_out, int out_size, void* d_ws, size_t ws_size,
                              hipStream_t stream) {
    const float* pred = (const float*)d_in[0];
    const float* gt   = (const float*)d_in[1];

    unsigned int* min_pred = (unsigned int*)d_ws;
    unsigned int* min_gt   = min_pred + BATCH * NPTS;

    // 0x7F7F7F7F = 3.39e38f acts as +inf
    hipMemsetAsync(d_ws, 0x7F, (size_t)2 * BATCH * NPTS * sizeof(unsigned int), stream);

    dim3 grid(NPTS / (BLOCK * Q), NPTS / CHUNK, 2 * BATCH);
    chamfer_min_kernel<<<grid, BLOCK, 0, stream>>>(pred, gt, min_pred, min_gt);

    chamfer_reduce_kernel<<<1, 1024, 0, stream>>>((const uint4*)min_pred, (float*)d_out);
}

// Round 3
// 41.264 us; speedup vs baseline: 4.4826x; 1.2213x over previous
//
#include <hip/hip_runtime.h>

#define BATCH 8
#define NPTS  4096
#define BLOCK 256
#define Q     8              // query points per thread
#define CHUNK 256            // target points staged in LDS per block
#define NPER  32768          // BATCH*NPTS points per cloud

// ws layout:
//   float4 pk[65536]   : packed [x,y,z,|p|^2]; pred at [b*4096+n], gt at 32768+...
//   uint   minbuf[65536]: min d2 bits; pred-queries first, gt-queries second

// K0: pack points into float4 (xyz + squared norm) and init min slots to +inf.
__global__ __launch_bounds__(256) void pack_init_kernel(
    const float* __restrict__ pred, const float* __restrict__ gt,
    float4* __restrict__ pk, unsigned int* __restrict__ minbuf)
{
    const int j = blockIdx.x * 256 + threadIdx.x;     // 0..65535
    const float* src = (j < NPER) ? pred : gt;
    const float* p = src + (size_t)(j & (NPER - 1)) * 3;
    const float x = p[0], y = p[1], z = p[2];
    pk[j] = make_float4(x, y, z, fmaf(x, x, fmaf(y, y, z * z)));
    minbuf[j] = 0x7F800000u;                          // +inf
}

// K1: per (pass,batch,chunk): each thread owns Q queries, loops CHUNK targets
// staged in LDS as float4 [gx,gy,gz,g2]. Tracks vmin = min(g2 - 2 p.g)
// (3 fma + 1 fmin per pair), folds |p|^2 at the end, clamps, atomicMin.
__global__ __launch_bounds__(BLOCK) void chamfer_min_kernel(
    const float4* __restrict__ pk, unsigned int* __restrict__ minbuf)
{
    const int z    = blockIdx.z;
    const int b    = z & 7;
    const int pass = z >> 3;
    const float4* query  = pk + (pass ? NPER : 0) + b * NPTS;
    const float4* target = pk + (pass ? 0 : NPER) + b * NPTS;
    unsigned int* outmin = minbuf + (pass ? NPER : 0) + b * NPTS;

    __shared__ float4 s[CHUNK];

    const int tid   = threadIdx.x;
    const int nbase = blockIdx.x * (BLOCK * Q);
    const int c0    = blockIdx.y * CHUNK;

    s[tid] = target[c0 + tid];                        // CHUNK == BLOCK

    float nx2[Q], ny2[Q], nz2[Q], p2[Q], mn[Q];
#pragma unroll
    for (int i = 0; i < Q; ++i) {
        const float4 qf = query[nbase + i * BLOCK + tid];
        nx2[i] = -2.0f * qf.x;
        ny2[i] = -2.0f * qf.y;
        nz2[i] = -2.0f * qf.z;
        p2[i]  = qf.w;
        mn[i]  = 3.0e38f;
    }
    __syncthreads();

#pragma unroll 4
    for (int t = 0; t < CHUNK; ++t) {
        const float4 g = s[t];
#pragma unroll
        for (int i = 0; i < Q; ++i) {
            float d = fmaf(g.x, nx2[i], g.w);
            d = fmaf(g.y, ny2[i], d);
            d = fmaf(g.z, nz2[i], d);
            mn[i] = fminf(mn[i], d);
        }
    }

#pragma unroll
    for (int i = 0; i < Q; ++i) {
        const float d2 = fmaxf(p2[i] + mn[i], 0.0f);  // = min squared distance
        atomicMin(&outmin[nbase + i * BLOCK + tid], __float_as_uint(d2));
    }
}

// K2: deterministic single-block reduction: (sum sqrt(min d2))/32768.
__global__ __launch_bounds__(1024) void chamfer_reduce_kernel(
    const uint4* __restrict__ mins,                   // 65536 uints = 16384 uint4
    float* __restrict__ out)
{
    const int tid = threadIdx.x;
    double acc = 0.0;
#pragma unroll
    for (int i = 0; i < 16; ++i) {
        const uint4 v = mins[tid + i * 1024];
        acc += (double)(sqrtf(__uint_as_float(v.x)) + sqrtf(__uint_as_float(v.y))
                      + sqrtf(__uint_as_float(v.z)) + sqrtf(__uint_as_float(v.w)));
    }
    __shared__ double sd[1024];
    sd[tid] = acc;
    __syncthreads();
    for (int off = 512; off > 0; off >>= 1) {
        if (tid < off) sd[tid] += sd[tid + off];
        __syncthreads();
    }
    if (tid == 0) out[0] = (float)(sd[0] / (double)NPER);
}

extern "C" void kernel_launch(void* const* d_in, const int* in_sizes, int n_in,
                              void* d_out, int out_size, void* d_ws, size_t ws_size,
                              hipStream_t stream) {
    const float* pred = (const float*)d_in[0];
    const float* gt   = (const float*)d_in[1];

    float4* pk            = (float4*)d_ws;            // 65536 float4 = 1 MB
    unsigned int* minbuf  = (unsigned int*)(pk + 2 * NPER); // 256 KB

    pack_init_kernel<<<2 * NPER / 256, 256, 0, stream>>>(pred, gt, pk, minbuf);

    dim3 grid(NPTS / (BLOCK * Q), NPTS / CHUNK, 2 * BATCH);
    chamfer_min_kernel<<<grid, BLOCK, 0, stream>>>(pk, minbuf);

    chamfer_reduce_kernel<<<1, 1024, 0, stream>>>((const uint4*)minbuf, (float*)d_out);
}